// Round 9
// baseline (579.476 us; speedup 1.0000x reference)
//
#include <hip/hip_runtime.h>
#include <math.h>

typedef __attribute__((ext_vector_type(4))) float f4;
typedef __attribute__((ext_vector_type(8))) _Float16 f16x8;
typedef __attribute__((ext_vector_type(8))) short bf16x8;
typedef __attribute__((ext_vector_type(4))) unsigned short u16x4;
typedef unsigned int u32;
typedef unsigned short u16;

#define DIMC  512
#define NITEM 2048
#define TK    10
#define WSP   (NITEM * DIMC)        // ws plane stride (u16 elems)

// ---------------- main kernel geometry ----------------
#define TPB    512                  // 8 waves: 4 item-groups x 2 px-groups
#define PXB    64                   // pixels per block
#define RIT    256                  // items per round
#define NRND   8
#define NSLICE 16                   // K-slices of 32 (K=512)

// ---------------- LDS layout (bytes) ----------------
//   q double-buffer: buf b at b*12288, plane p at +p*4096  [0, 24576)
//   planes: 0 = fp16(x), 1 = bf16(x), 2 = bf16(x - fp16(x))
//   S overlay [256][66] f32 at 0..67583 — overlays q bufs; phase-separated
//   (q writes happen between the post-scan barrier and the drain barrier;
//   S lives from drain to scan end). merge arrays overlay S low region.
//   NO mp staging: A-fragments load direct from ws (no intra-block reuse).
#define QB_SZ  12288
#define Q_PL   4096
#define SSTR   66
#define LDS_BYTES 67584  // 66 KB -> 2 blocks/CU
// merge overlay (float indices from base 0)
#define MV_F 0        // [64][8][10] vals
#define MI_F 5120     // [64][8][10] idx
#define MM_F 10240    // [64][8] max
#define MS_F 10752    // [64][8] sum
#define WB_F 11264    // [64][10] weights
#define IB_F 11904    // [64][10] indices

// bank-spread swizzle key for q fragment tiles (2-way residual = free)
#define KSWZ(i) (((i) ^ ((i) >> 2)) & 3)

union h16 { _Float16 h; u16 u; };

__device__ __forceinline__ u32 bf16_rne(float f) {
    u32 u = __float_as_uint(f);
    return (u + 0x7fffu + ((u >> 16) & 1u)) >> 16;
}

// mixed split: f = fp16(f) + residual; planes {fp16(f), bf16(f), bf16(res)}.
// m*q ~= h(m)h(q) + b(m)b(qres) + b(mres)b(q)  (all true-scale -> one acc)
__device__ __forceinline__ void split3(float f, u16& ph, u16& pb, u16& pr) {
    h16 a; a.h = (_Float16)f;
    float f0 = (float)a.h;
    ph = a.u;
    pb = (u16)bf16_rne(f);
    pr = (u16)bf16_rne(f - f0);
}

// mempool fp32 -> 3 planes in ws, FRAGMENT-MAJOR layout.
// Block sizes: group (16 items) = 16 slices * 512 u16 = 8192 u16;
// slice within group = 512 u16 (16 items x 32 k).  FIX vs r8: slice stride
// is 512 (was 1024, which aliased (g, s>=8) onto (g+1, s-8) -> write-write
// collisions corrupted half the fragments).
//   u16 addr = plane*WSP + (i>>4)*8192 + s*512 + (lh*16 + (i&15))*8 + pair*4 + j
// for k = s*32 + kl, lh=(kl>>2)&3, pair=kl>>4, j=kl&3.  A wave's frag load for
// (group g, slice s) is ws + pl*WSP + g*8192 + s*512 + lane*8 — contiguous
// 1 KB per 64-lane b128 load. Same k-permutation as the q side
// (correctness-invariant to true HW k-grouping since A and B share it).
__global__ __launch_bounds__(256)
void preconv_kernel(const float* __restrict__ mp, u16* __restrict__ ws)
{
    int idx = (blockIdx.x * 256 + threadIdx.x) * 4;   // 1024 blocks -> exact
    int i  = idx >> 9;
    int k0 = idx & 511;                               // 4-aligned -> j = e
    f4 v = *(const f4*)(mp + (size_t)i * 512 + k0);
    int s  = k0 >> 5, kl = k0 & 31;
    int lh = (kl >> 2) & 3, pair = kl >> 4;
    u16x4 pH, pB, pR;
#pragma unroll
    for (int e = 0; e < 4; ++e) {
        u16 h, b, r; split3(v[e], h, b, r);
        pH[e] = h; pB[e] = b; pR[e] = r;
    }
    size_t base = (size_t)(i >> 4) * 8192 + (size_t)s * 512
                + (size_t)(lh * 16 + (i & 15)) * 8 + pair * 4;
    *(u16x4*)(ws + 0 * WSP + base) = pH;
    *(u16x4*)(ws + 1 * WSP + base) = pB;
    *(u16x4*)(ws + 2 * WSP + base) = pR;
}

__global__ __launch_bounds__(TPB, 4)
void memorize_mfma(const float* __restrict__ x0, const float* __restrict__ x1,
                   const float* __restrict__ mp, const u16* __restrict__ ws,
                   float* __restrict__ out)
{
    extern __shared__ char ldsb[];
    float* ldsf = (float*)ldsb;

    const int t    = threadIdx.x;
    const int lane = t & 63;
    const int w    = t >> 6;            // wave 0..7
    const int blk  = blockIdx.x;        // 0..511
    const int img  = blk >> 4;          // 0..31
    const int n0   = (blk & 15) * PXB;  // pixel base (HW = 1024)
    const int b    = img & 15;

    const float* x  = (img < 16) ? x0 : x1;
    const float* xb = x + (size_t)b * (DIMC * 1024);
    float* ob = out + (img < 16 ? (size_t)0 : (size_t)16 * DIMC * 1024)
                    + (size_t)b * (DIMC * 1024);

    const int l15 = lane & 15;
    const int lh  = lane >> 4;
    const int ksw = lh ^ KSWZ(l15);     // swizzled 16B slot for q frag reads
    const int ig  = w >> 1;             // item group: items ig*64..+63
    const int pg  = w & 1;              // px group:   px pg*32..+31

    // scan mapping: 8 groups of 32 items per round per pixel
    const int qp = t & 63;
    const int g  = t >> 6;

    float tv[TK]; int tix[TK];
#pragma unroll
    for (int q = 0; q < TK; ++q) { tv[q] = -INFINITY; tix[q] = 0x7fffffff; }
    float rm = -INFINITY, rs = 0.0f;

    // q staging mapping: thread -> (k-local scl, 4 px)
    const int scl  = t & 31;
    const int spx  = (t >> 5) << 2;     // 0..60
    const int spos = (((scl >> 2) & 3) << 3) + ((scl >> 4) << 2) + (scl & 3);
    const int sslot = spos >> 3;        // true 16B k-slot of this write
    const int soff  = (spos & 7) << 1;  // byte offset within slot

    // a-side direct-load base (u16 units): + pl*WSP + (r*16 + ig*4 + it)*8192
    const u16* aw = ws + (size_t)lane * 8 + (size_t)(ig * 4) * 8192;

    // q fragment read base: px = pg*32 + pt*16 + l15, slot ksw
    const int qfb = (pg << 11) + (l15 << 6) + (ksw << 4);

#define STAGE_Q(S, BUF)                                                        \
    {                                                                          \
        const float* src = xb + (size_t)(((S) << 5) + scl) * 1024 + n0 + spx;  \
        f4 v = *(const f4*)src;                                                \
        _Pragma("unroll")                                                      \
        for (int e = 0; e < 4; ++e) {                                          \
            int px = spx + e;                                                  \
            u16 h, bb, rr; split3(v[e], h, bb, rr);                            \
            int ro = (BUF) * QB_SZ + (px << 6)                                 \
                   + (((sslot ^ KSWZ(px)) << 4) | soff);                       \
            *(u16*)(ldsb + ro)            = h;                                 \
            *(u16*)(ldsb + ro + Q_PL)     = bb;                                \
            *(u16*)(ldsb + ro + 2 * Q_PL) = rr;                                \
        }                                                                      \
    }

#define ALOAD(IT, S)                                                           \
    {                                                                          \
        const u16* ap = ar + ((size_t)(IT) << 13) + ((S) << 9);                \
        aH[IT] = *(const f16x8*) (ap + 0 * WSP);                               \
        aB[IT] = *(const bf16x8*)(ap + 1 * WSP);                               \
        aR[IT] = *(const bf16x8*)(ap + 2 * WSP);                               \
    }

#pragma unroll 1
    for (int r = 0; r < NRND; ++r) {
        const u16* ar = aw + ((size_t)r << 17);   // + r*16 groups * 8192
        f4 acc[4][2];
#pragma unroll
        for (int it = 0; it < 4; ++it)
#pragma unroll
            for (int pt = 0; pt < 2; ++pt) acc[it][pt] = (f4){0.f, 0.f, 0.f, 0.f};

        __syncthreads();           // prev round's scan reads done (S dead)
        STAGE_Q(0, 0)
        __syncthreads();

#pragma unroll 1
        for (int s = 0; s < NSLICE; ++s) {
            const int cur = s & 1;

            // issue first half of A-frag loads (latency hides under q-stage)
            f16x8 aH[4]; bf16x8 aB[4], aR[4];
            ALOAD(0, s)
            ALOAD(1, s)

            // stage next q slice into the other buffer
            if (s + 1 < NSLICE) STAGE_Q(s + 1, cur ^ 1)

            // q fragment reads from current buffer
            const char* qc = ldsb + cur * QB_SZ + qfb;
            f16x8 qH[2]; bf16x8 qB[2], qR[2];
#pragma unroll
            for (int pt = 0; pt < 2; ++pt) {
                qH[pt] = *(const f16x8*) (qc + 0 * Q_PL + pt * 1024);
                qB[pt] = *(const bf16x8*)(qc + 1 * Q_PL + pt * 1024);
                qR[pt] = *(const bf16x8*)(qc + 2 * Q_PL + pt * 1024);
            }

            // MFMA: 8 tiles x 3 split-products; stagger remaining A-loads
#pragma unroll
            for (int it = 0; it < 4; ++it) {
                if (it < 2) ALOAD(it + 2, s)
#pragma unroll
                for (int pt = 0; pt < 2; ++pt) {
                    f4 c = acc[it][pt];
                    c = __builtin_amdgcn_mfma_f32_16x16x32_f16 (aH[it], qH[pt], c, 0, 0, 0);
                    c = __builtin_amdgcn_mfma_f32_16x16x32_bf16(aB[it], qR[pt], c, 0, 0, 0);
                    c = __builtin_amdgcn_mfma_f32_16x16x32_bf16(aR[it], qB[pt], c, 0, 0, 0);
                    acc[it][pt] = c;
                }
            }
            __syncthreads();   // q(s+1) staged by all; q(s) reads done by all
        }

        // ---- drain accs to S overlay: row=item-local, col=px ----
#pragma unroll
        for (int it = 0; it < 4; ++it) {
#pragma unroll
            for (int pt = 0; pt < 2; ++pt) {
                int row = (ig << 6) + (it << 4) + (lh << 2);   // + reg
                int col = (pg << 5) + (pt << 4) + l15;
                float* sp = ldsf + row * SSTR + col;
                sp[0 * SSTR] = acc[it][pt][0];
                sp[1 * SSTR] = acc[it][pt][1];
                sp[2 * SSTR] = acc[it][pt][2];
                sp[3 * SSTR] = acc[it][pt][3];
            }
        }
        __syncthreads();

        // ---- scan sweep 1: max + guarded top-10 insert (32 items/thread) ----
        float mloc = rm;
#pragma unroll 4
        for (int jj = 0; jj < 32; ++jj) {
            int   il = (g << 5) + jj;
            float v  = ldsf[il * SSTR + qp];
            mloc = fmaxf(mloc, v);
            if (v > tv[TK - 1]) {
                int   id = r * RIT + il;
                float cv = v; int ci = id;
#pragma unroll
                for (int q = 0; q < TK; ++q) {
                    bool  gt = cv > tv[q];
                    float nv = gt ? tv[q]  : cv;
                    int   ni = gt ? tix[q] : ci;
                    tv[q]  = gt ? cv : tv[q];
                    tix[q] = gt ? ci : tix[q];
                    cv = nv; ci = ni;
                }
            }
        }
        rs *= __expf(rm - mloc);   // round 0: rs==0 -> ok
        rm = mloc;
        // ---- scan sweep 2: exp-sum at fixed max ----
#pragma unroll 4
        for (int jj = 0; jj < 32; ++jj) {
            int   il = (g << 5) + jj;
            float v  = ldsf[il * SSTR + qp];
            rs += __expf(v - rm);
        }
    }

    // ---- dump per-thread partials for merge ----
    __syncthreads();
    {
#pragma unroll
        for (int q = 0; q < TK; ++q) {
            ldsf[MV_F + (qp * 8 + g) * TK + q] = tv[q];
            ldsf[MI_F + (qp * 8 + g) * TK + q] = __int_as_float(tix[q]);
        }
        ldsf[MM_F + qp * 8 + g] = rm;
        ldsf[MS_F + qp * 8 + g] = rs;
    }
    __syncthreads();

    // ---- merge 8 partial lists per pixel; double softmax ----
    if (t < 64) {
        const int p = t;
        float gm[8], gs[8];
#pragma unroll
        for (int G = 0; G < 8; ++G) {
            gm[G] = ldsf[MM_F + p * 8 + G];
            gs[G] = ldsf[MS_F + p * 8 + G];
        }
        float mstar = gm[0];
#pragma unroll
        for (int G = 1; G < 8; ++G) mstar = fmaxf(mstar, gm[G]);
        float Z = 0.0f;
#pragma unroll
        for (int G = 0; G < 8; ++G) Z += gs[G] * __expf(gm[G] - mstar);

        int h0=0,h1=0,h2=0,h3=0,h4=0,h5=0,h6=0,h7=0;
        float ov[TK]; int oi[TK];
#pragma unroll
        for (int o = 0; o < TK; ++o) {
            float bv = -INFINITY; int bi = 0x7fffffff; int bg = 0;
#define SEL(G, HG)                                                               \
            {                                                                    \
                float v  = ldsf[MV_F + (p * 8 + G) * TK + (HG)];                 \
                int   id = __float_as_int(ldsf[MI_F + (p * 8 + G) * TK + (HG)]); \
                if (v > bv || (v == bv && id < bi)) { bv = v; bi = id; bg = G; } \
            }
            SEL(0, h0) SEL(1, h1) SEL(2, h2) SEL(3, h3)
            SEL(4, h4) SEL(5, h5) SEL(6, h6) SEL(7, h7)
#undef SEL
            ov[o] = bv; oi[o] = bi;
            h0 += (bg == 0); h1 += (bg == 1); h2 += (bg == 2); h3 += (bg == 3);
            h4 += (bg == 4); h5 += (bg == 5); h6 += (bg == 6); h7 += (bg == 7);
        }
        float pv[TK];
#pragma unroll
        for (int o = 0; o < TK; ++o) pv[o] = __expf(ov[o] - mstar) / Z;
        float pmax = pv[0];
        float wgt[TK]; float W = 0.0f;
#pragma unroll
        for (int o = 0; o < TK; ++o) { wgt[o] = __expf(pv[o] - pmax); W += wgt[o]; }
#pragma unroll
        for (int o = 0; o < TK; ++o) {
            ldsf[WB_F + p * TK + o] = wgt[o] / W;
            ldsf[IB_F + p * TK + o] = __int_as_float(oi[o]);
        }
    }
    __syncthreads();

    // ---- epilogue: out[:, c, n] = sum_k w_k * mempool[idx_k][c] ----
    {
        const int ep = t & 63, cg = t >> 6;   // 8 c-groups x 64 channels
        float wr[TK]; const float* rows[TK];
#pragma unroll
        for (int o = 0; o < TK; ++o) {
            wr[o]   = ldsf[WB_F + ep * TK + o];
            rows[o] = mp + (size_t)__float_as_int(ldsf[IB_F + ep * TK + o]) * DIMC;
        }
        float* obase = ob + n0 + ep;
#pragma unroll 4
        for (int cc = 0; cc < 16; ++cc) {
            int c = cg * 64 + cc * 4;
            f4 a = {0.0f, 0.0f, 0.0f, 0.0f};
#pragma unroll
            for (int o = 0; o < TK; ++o) {
                f4 rv = *(const f4*)(rows[o] + c);
#pragma unroll
                for (int z = 0; z < 4; ++z) a[z] = fmaf(wr[o], rv[z], a[z]);
            }
#pragma unroll
            for (int z = 0; z < 4; ++z) obase[(size_t)(c + z) * 1024] = a[z];
        }
    }
#undef STAGE_Q
#undef ALOAD
}

extern "C" void kernel_launch(void* const* d_in, const int* in_sizes, int n_in,
                              void* d_out, int out_size, void* d_ws, size_t ws_size,
                              hipStream_t stream) {
    const float* x0  = (const float*)d_in[0];
    const float* x1  = (const float*)d_in[1];
    const float* mpl = (const float*)d_in[2];
    float* out = (float*)d_out;
    u16* ws = (u16*)d_ws;

    preconv_kernel<<<dim3(1024), dim3(256), 0, stream>>>(mpl, ws);
    memorize_mfma<<<dim3(512), dim3(TPB), LDS_BYTES, stream>>>(x0, x1, mpl, ws, out);
}